// Round 2
// baseline (227.226 us; speedup 1.0000x reference)
//
#include <hip/hip_runtime.h>

// Net_19387482374339: fused 3-step LSTM (HID=IN=1) + linear head over groups of 6 seqs.
// One thread per output element (group of 6 sequences, 18 x-values, 18 LSTM steps).
//
// R2 change: x is read through LDS with coalesced staging. R1 read 72B/thread
// directly (lanes 72B apart -> ~72 cache-line transactions per load instr,
// ~648/wave -> L1-pipe bound ~85us). Now: 9 coalesced float2 loads/thread into
// an 18KiB LDS slab (9 transactions/wave), then per-thread LDS reads
// (stride-18 dwords = 4-way bank conflict = 1.58x, negligible).
//
// Math (trans-op minimization, 7 trans/timestep: 5 exp2 + 2 rcp):
//   sigmoid(z) = 1/(1+exp2(-L*z)), tanh(z) = (E-1)/(E+1), E = exp2(2L*z), L = log2(e)
//   Gate weights pre-scaled by -L (i,f,o) / +2L (g).
//   c_new = [c*(1+Ei)(1+Eg) + (Eg-1)*(1+Ef)] * rcp((1+Ei)(1+Eg)(1+Ef))
//   h     = (Ec-1) * rcp((1+Eo)(Ec+1))

constexpr float L2E = 1.4426950408889634f;

#if __has_builtin(__builtin_amdgcn_exp2f)
#define EXP2(x) __builtin_amdgcn_exp2f(x)
#else
#define EXP2(x) exp2f(x)
#endif
#if __has_builtin(__builtin_amdgcn_rcpf)
#define RCP(x) __builtin_amdgcn_rcpf(x)
#else
#define RCP(x) (1.0f / (x))
#endif

__global__ __launch_bounds__(256) void lstm_head_kernel(
    const float* __restrict__ x,
    const float* __restrict__ w_ih, const float* __restrict__ w_hh,
    const float* __restrict__ b_ih, const float* __restrict__ b_hh,
    const float* __restrict__ w_lin, const float* __restrict__ b_lin,
    float* __restrict__ out, int n_groups)
{
    __shared__ float xs_lds[256 * 18];  // 18 KiB -> 8 blocks/CU still fits LDS

    const int tid = threadIdx.x;
    const int g   = blockIdx.x * 256 + tid;

    // ---- coalesced staging: block slab = 4608 floats = 2304 float2 ----
    {
        const size_t slab_f2 = (size_t)blockIdx.x * 2304;     // float2 units
        const size_t total_f2 = (size_t)n_groups * 9;
        const float2* xp = reinterpret_cast<const float2*>(x);
        float2* lp = reinterpret_cast<float2*>(xs_lds);
#pragma unroll
        for (int k = 0; k < 9; ++k) {
            size_t idx = slab_f2 + (size_t)k * 256 + tid;
            if (idx < total_f2) lp[k * 256 + tid] = xp[idx];
        }
    }
    __syncthreads();

    // ---- uniform params (scalar loads); pre-scaled ----
    float Ax[4], Ah[4], Ab[4];
#pragma unroll
    for (int k = 0; k < 4; ++k) {
        const float sc = (k == 2) ? (2.0f * L2E) : (-L2E);
        Ax[k] = sc * w_ih[k];
        Ah[k] = sc * w_hh[k];
        Ab[k] = sc * (b_ih[k] + b_hh[k]);
    }
    float wl[18];
#pragma unroll
    for (int k = 0; k < 18; ++k) wl[k] = w_lin[k];
    const float bl = b_lin[0];

    if (g >= n_groups) return;

    // ---- per-thread 18 x-values from LDS ----
    float xs[18];
    {
        const float* mine = xs_lds + tid * 18;
#pragma unroll
        for (int k = 0; k < 18; ++k) xs[k] = mine[k];
    }

    float acc = bl;
#pragma unroll
    for (int j = 0; j < 6; ++j) {
        // ---- t = 0: h=0, c=0 (f-gate dead) ----
        const float x0 = xs[3 * j];
        float ai = fmaf(x0, Ax[0], Ab[0]);
        float ag = fmaf(x0, Ax[2], Ab[2]);
        float ao = fmaf(x0, Ax[3], Ab[3]);
        float Ei = EXP2(ai), Eg = EXP2(ag), Eo = EXP2(ao);
        float t1 = Ei + 1.0f, t2 = Eg + 1.0f;
        float c = (t2 - 2.0f) * RCP(t1 * t2);          // i * tanh(g)
        float Ec = EXP2(2.0f * L2E * c);
        float t5 = Ec + 1.0f;
        float h = (t5 - 2.0f) * RCP((Eo + 1.0f) * t5); // o * tanh(c)
        acc = fmaf(h, wl[3 * j], acc);

        // ---- t = 1, 2 ----
#pragma unroll
        for (int t = 1; t < 3; ++t) {
            const float xv = xs[3 * j + t];
            float bi = fmaf(xv, Ax[0], Ab[0]);
            float bf = fmaf(xv, Ax[1], Ab[1]);
            float bg = fmaf(xv, Ax[2], Ab[2]);
            float bo = fmaf(xv, Ax[3], Ab[3]);
            float ai2 = fmaf(h, Ah[0], bi);
            float af2 = fmaf(h, Ah[1], bf);
            float ag2 = fmaf(h, Ah[2], bg);
            float ao2 = fmaf(h, Ah[3], bo);
            float Ei2 = EXP2(ai2), Ef2 = EXP2(af2), Eg2 = EXP2(ag2), Eo2 = EXP2(ao2);
            float u1 = Ei2 + 1.0f, u2 = Eg2 + 1.0f, u3 = Ef2 + 1.0f;
            float IG = u1 * u2;
            float R  = RCP(IG * u3);
            float num = fmaf(c, IG, (u2 - 2.0f) * u3);
            c = num * R;                                // f*c + i*tanh(g)
            float Ec2 = EXP2(2.0f * L2E * c);
            float v5 = Ec2 + 1.0f;
            h = (v5 - 2.0f) * RCP((Eo2 + 1.0f) * v5);  // o * tanh(c)
            acc = fmaf(h, wl[3 * j + t], acc);
        }
    }
    out[g] = acc;
}

extern "C" void kernel_launch(void* const* d_in, const int* in_sizes, int n_in,
                              void* d_out, int out_size, void* d_ws, size_t ws_size,
                              hipStream_t stream) {
    const float* x     = (const float*)d_in[0];
    const float* w_ih  = (const float*)d_in[1];
    const float* w_hh  = (const float*)d_in[2];
    const float* b_ih  = (const float*)d_in[3];
    const float* b_hh  = (const float*)d_in[4];
    const float* w_lin = (const float*)d_in[5];
    const float* b_lin = (const float*)d_in[6];
    float* out = (float*)d_out;

    const int n_groups = in_sizes[0] / 18;  // B/6 = 2097152
    const int grid = (n_groups + 255) / 256;
    lstm_head_kernel<<<grid, 256, 0, stream>>>(
        x, w_ih, w_hh, b_ih, b_hh, w_lin, b_lin, out, n_groups);
}

// Round 3
// 224.572 us; speedup vs baseline: 1.0118x; 1.0118x over previous
//
#include <hip/hip_runtime.h>

// Net_19387482374339: fused 3-step LSTM (HID=IN=1) + linear head over groups of 6 seqs.
// One thread per output group; the 6 independent sequences run as 3 float2-packed
// pairs (targets v_pk_fma_f32 / packed VOP3P fp32 on gfx950) -> non-trans VALU ~halved.
//
// Trans minimization (per pair per timestep: 10 exp2 + 2 rcp, vs 14 unpacked):
//   sigmoid(z) = 1/(1+exp2(-L*z)), tanh(z) = (E-1)/(E+1), E = exp2(2L*z), L = log2(e)
//   Gate weights pre-scaled by -L (i,f,o) / +2L (g).
//   Cell kept in scaled domain C = 2L*c:
//     C_new = (C*IG + (2L*u2-4L)*u3) * rcp(IG*u3),  u1=Ei+1,u2=Eg+1,u3=Ef+1, IG=u1*u2
//     h     = (Ec-1) * rcp((Eo+1)(Ec+1)),           Ec = exp2(C_new)
//   Pair-merged reciprocal: R=rcp(a*b); 1/a=R*b, 1/b=R*a  (1 trans + 3 mul for 2 rcps).

typedef float v2f __attribute__((ext_vector_type(2)));

constexpr float L2E = 1.4426950408889634f;

#if __has_builtin(__builtin_amdgcn_exp2f)
#define EXP2(x) __builtin_amdgcn_exp2f(x)
#else
#define EXP2(x) exp2f(x)
#endif
#if __has_builtin(__builtin_amdgcn_rcpf)
#define RCP(x) __builtin_amdgcn_rcpf(x)
#else
#define RCP(x) (1.0f / (x))
#endif

static __device__ __forceinline__ v2f vexp2(v2f z) {
    v2f r; r.x = EXP2(z.x); r.y = EXP2(z.y); return r;
}
// both reciprocals from one rcp: R=rcp(x*y); 1/x=R*y, 1/y=R*x (~3 ulp rel, fine at 6e-3)
static __device__ __forceinline__ v2f vrcp2(v2f d) {
    float R = RCP(d.x * d.y);
    v2f r; r.x = R * d.y; r.y = R * d.x; return r;
}
static __device__ __forceinline__ v2f vfma(v2f a, v2f b, v2f c) {
    return __builtin_elementwise_fma(a, b, c);
}

__global__ __launch_bounds__(256) void lstm_head_kernel(
    const float* __restrict__ x,
    const float* __restrict__ w_ih, const float* __restrict__ w_hh,
    const float* __restrict__ b_ih, const float* __restrict__ b_hh,
    const float* __restrict__ w_lin, const float* __restrict__ b_lin,
    float* __restrict__ out, int n_groups)
{
    __shared__ float xs_lds[256 * 18];  // 18 KiB

    const int tid = threadIdx.x;
    const int g   = blockIdx.x * 256 + tid;

    // ---- coalesced staging: block slab = 4608 floats = 2304 float2 ----
    {
        const size_t slab_f2  = (size_t)blockIdx.x * 2304;
        const size_t total_f2 = (size_t)n_groups * 9;
        const float2* xp = reinterpret_cast<const float2*>(x);
        float2* lp = reinterpret_cast<float2*>(xs_lds);
#pragma unroll
        for (int k = 0; k < 9; ++k) {
            size_t idx = slab_f2 + (size_t)k * 256 + tid;
            if (idx < total_f2) lp[k * 256 + tid] = xp[idx];
        }
    }
    __syncthreads();

    // ---- uniform params (scalar loads), pre-scaled, broadcast to v2 ----
    v2f vAx[4], vAh[4], vAb[4];
#pragma unroll
    for (int k = 0; k < 4; ++k) {
        const float sc = (k == 2) ? (2.0f * L2E) : (-L2E);
        const float ax = sc * w_ih[k];
        const float ah = sc * w_hh[k];
        const float ab = sc * (b_ih[k] + b_hh[k]);
        vAx[k].x = ax; vAx[k].y = ax;
        vAh[k].x = ah; vAh[k].y = ah;
        vAb[k].x = ab; vAb[k].y = ab;
    }
    v2f wl2[3][3];
#pragma unroll
    for (int p = 0; p < 3; ++p)
#pragma unroll
        for (int t = 0; t < 3; ++t) {
            wl2[p][t].x = w_lin[6 * p + t];
            wl2[p][t].y = w_lin[6 * p + t + 3];
        }
    const float bl = b_lin[0];

    const v2f one  = {1.0f, 1.0f};
    const v2f vL2  = {2.0f * L2E, 2.0f * L2E};
    const v2f vNL4 = {-4.0f * L2E, -4.0f * L2E};

    if (g >= n_groups) return;

    const float* mine = xs_lds + tid * 18;

    v2f acc = {0.0f, 0.0f};
#pragma unroll
    for (int p = 0; p < 3; ++p) {
        // pair = sequences (2p, 2p+1); component k of v2 = seq 2p+k
        // per-time x pairs: offsets (6p+t, 6p+t+3) -> ds_read2_b32-friendly
        v2f xt[3];
#pragma unroll
        for (int t = 0; t < 3; ++t) {
            xt[t].x = mine[6 * p + t];
            xt[t].y = mine[6 * p + t + 3];
        }

        // ---- t = 0: h=0, c=0 (f-gate dead) ----
        v2f zi = vfma(xt[0], vAx[0], vAb[0]);
        v2f zg = vfma(xt[0], vAx[2], vAb[2]);
        v2f zo = vfma(xt[0], vAx[3], vAb[3]);
        v2f Ei = vexp2(zi), Eg = vexp2(zg), Eo = vexp2(zo);
        v2f u1 = Ei + one, u2 = Eg + one;
        v2f R1 = vrcp2(u1 * u2);
        v2f C  = vfma(u2, vL2, vNL4) * R1;      // 2L * i*tanh(g)
        v2f Ec = vexp2(C);
        v2f em1 = Ec - one, v5 = Ec + one;
        v2f R2 = vrcp2((Eo + one) * v5);
        v2f h  = em1 * R2;                       // o * tanh(c)
        acc = vfma(h, wl2[p][0], acc);

        // ---- t = 1, 2 ----
#pragma unroll
        for (int t = 1; t < 3; ++t) {
            v2f xv = xt[t];
            v2f ziA = vfma(h, vAh[0], vfma(xv, vAx[0], vAb[0]));
            v2f zfA = vfma(h, vAh[1], vfma(xv, vAx[1], vAb[1]));
            v2f zgA = vfma(h, vAh[2], vfma(xv, vAx[2], vAb[2]));
            v2f zoA = vfma(h, vAh[3], vfma(xv, vAx[3], vAb[3]));
            v2f EiA = vexp2(ziA), EfA = vexp2(zfA), EgA = vexp2(zgA), EoA = vexp2(zoA);
            v2f w1 = EiA + one, w2 = EgA + one, w3 = EfA + one;
            v2f IG = w1 * w2;
            v2f Ra = vrcp2(IG * w3);
            v2f tt = vfma(w2, vL2, vNL4) * w3;   // (2L*u2 - 4L)*u3
            v2f num = vfma(C, IG, tt);
            C = num * Ra;                        // scaled cell: 2L*(f*c + i*tanh(g))
            v2f EcA = vexp2(C);
            v2f e1 = EcA - one, e2 = EcA + one;
            v2f Rb = vrcp2((EoA + one) * e2);
            h = e1 * Rb;                         // o * tanh(c)
            acc = vfma(h, wl2[p][t], acc);
        }
    }
    out[g] = acc.x + acc.y + bl;
}

extern "C" void kernel_launch(void* const* d_in, const int* in_sizes, int n_in,
                              void* d_out, int out_size, void* d_ws, size_t ws_size,
                              hipStream_t stream) {
    const float* x     = (const float*)d_in[0];
    const float* w_ih  = (const float*)d_in[1];
    const float* w_hh  = (const float*)d_in[2];
    const float* b_ih  = (const float*)d_in[3];
    const float* b_hh  = (const float*)d_in[4];
    const float* w_lin = (const float*)d_in[5];
    const float* b_lin = (const float*)d_in[6];
    float* out = (float*)d_out;

    const int n_groups = in_sizes[0] / 18;  // B/6 = 2097152
    const int grid = (n_groups + 255) / 256;
    lstm_head_kernel<<<grid, 256, 0, stream>>>(
        x, w_ih, w_hh, b_ih, b_hh, w_lin, b_lin, out, n_groups);
}

// Round 4
// 218.580 us; speedup vs baseline: 1.0396x; 1.0274x over previous
//
#include <hip/hip_runtime.h>

// Net_19387482374339: fused 3-step LSTM (HID=IN=1) + linear head over groups of 6 seqs.
// One thread per output group; 6 sequences as 3 float2-packed pairs (v_pk_* fp32).
//
// R4: discriminating probe = minimal kernel. Drop LDS staging + __syncthreads
// (R2 proved staged==direct; barrier forces vmcnt/lgkmcnt drain), keep R3's
// packed math + merged reciprocals. 9 direct float2 loads (72B/thread, 8B-aligned).
// Theory: kernel sits at the mandatory-HBM floor (151MB read + 8.4MB write
// ~ 24us @ 6.6TB/s) under a ~190us fixed harness floor (576MiB ws-poison fill
// ~87us + 151MB input-restore copy); hence R1/R2/R3 all benched identical.
// If this is neutral too, the kernel is at its memory roofline.
//
// Math (per pair per step: 10 exp2 + 2 rcp):
//   sigmoid(z)=1/(1+exp2(-L*z)), tanh(z)=(E-1)/(E+1), E=exp2(2L*z), L=log2(e)
//   gate weights pre-scaled by -L (i,f,o) / +2L (g); cell kept scaled C=2L*c.
//   C_new = (C*IG + (2L*u2-4L)*u3) * rcp(IG*u3);  h = (Ec-1)*rcp((Eo+1)(Ec+1))
//   vrcp2: R=rcp(a*b); 1/a=R*b, 1/b=R*a  (one trans for two reciprocals).

typedef float v2f __attribute__((ext_vector_type(2)));

constexpr float L2E = 1.4426950408889634f;

#if __has_builtin(__builtin_amdgcn_exp2f)
#define EXP2(x) __builtin_amdgcn_exp2f(x)
#else
#define EXP2(x) exp2f(x)
#endif
#if __has_builtin(__builtin_amdgcn_rcpf)
#define RCP(x) __builtin_amdgcn_rcpf(x)
#else
#define RCP(x) (1.0f / (x))
#endif

static __device__ __forceinline__ v2f vexp2(v2f z) {
    v2f r; r.x = EXP2(z.x); r.y = EXP2(z.y); return r;
}
static __device__ __forceinline__ v2f vrcp2(v2f d) {
    float R = RCP(d.x * d.y);
    v2f r; r.x = R * d.y; r.y = R * d.x; return r;
}
static __device__ __forceinline__ v2f vfma(v2f a, v2f b, v2f c) {
    return __builtin_elementwise_fma(a, b, c);
}

__global__ __launch_bounds__(256) void lstm_head_kernel(
    const float* __restrict__ x,
    const float* __restrict__ w_ih, const float* __restrict__ w_hh,
    const float* __restrict__ b_ih, const float* __restrict__ b_hh,
    const float* __restrict__ w_lin, const float* __restrict__ b_lin,
    float* __restrict__ out, int n_groups)
{
    const int g = blockIdx.x * 256 + threadIdx.x;

    // ---- uniform params (scalar loads), pre-scaled, broadcast to v2 ----
    v2f vAx[4], vAh[4], vAb[4];
#pragma unroll
    for (int k = 0; k < 4; ++k) {
        const float sc = (k == 2) ? (2.0f * L2E) : (-L2E);
        const float ax = sc * w_ih[k];
        const float ah = sc * w_hh[k];
        const float ab = sc * (b_ih[k] + b_hh[k]);
        vAx[k].x = ax; vAx[k].y = ax;
        vAh[k].x = ah; vAh[k].y = ah;
        vAb[k].x = ab; vAb[k].y = ab;
    }
    v2f wl2[3][3];
#pragma unroll
    for (int p = 0; p < 3; ++p)
#pragma unroll
        for (int t = 0; t < 3; ++t) {
            wl2[p][t].x = w_lin[6 * p + t];
            wl2[p][t].y = w_lin[6 * p + t + 3];
        }
    const float bl = b_lin[0];

    const v2f one  = {1.0f, 1.0f};
    const v2f vL2  = {2.0f * L2E, 2.0f * L2E};
    const v2f vNL4 = {-4.0f * L2E, -4.0f * L2E};

    if (g >= n_groups) return;

    // ---- 18 contiguous x floats, 9 x dwordx2 (72B/thread, 8B-aligned) ----
    float xs[18];
    {
        const float2* xp = reinterpret_cast<const float2*>(x) + (size_t)g * 9;
#pragma unroll
        for (int k = 0; k < 9; ++k) {
            float2 v = xp[k];
            xs[2 * k]     = v.x;
            xs[2 * k + 1] = v.y;
        }
    }

    v2f acc = {0.0f, 0.0f};
#pragma unroll
    for (int p = 0; p < 3; ++p) {
        // pair p = sequences (2p, 2p+1): x offsets (6p+t, 6p+t+3)
        v2f xt[3];
#pragma unroll
        for (int t = 0; t < 3; ++t) {
            xt[t].x = xs[6 * p + t];
            xt[t].y = xs[6 * p + t + 3];
        }

        // ---- t = 0: h=0, c=0 (f-gate dead) ----
        v2f zi = vfma(xt[0], vAx[0], vAb[0]);
        v2f zg = vfma(xt[0], vAx[2], vAb[2]);
        v2f zo = vfma(xt[0], vAx[3], vAb[3]);
        v2f Ei = vexp2(zi), Eg = vexp2(zg), Eo = vexp2(zo);
        v2f u1 = Ei + one, u2 = Eg + one;
        v2f R1 = vrcp2(u1 * u2);
        v2f C  = vfma(u2, vL2, vNL4) * R1;      // 2L * i*tanh(g)
        v2f Ec = vexp2(C);
        v2f em1 = Ec - one, v5 = Ec + one;
        v2f R2 = vrcp2((Eo + one) * v5);
        v2f h  = em1 * R2;                       // o * tanh(c)
        acc = vfma(h, wl2[p][0], acc);

        // ---- t = 1, 2 ----
#pragma unroll
        for (int t = 1; t < 3; ++t) {
            v2f xv = xt[t];
            v2f ziA = vfma(h, vAh[0], vfma(xv, vAx[0], vAb[0]));
            v2f zfA = vfma(h, vAh[1], vfma(xv, vAx[1], vAb[1]));
            v2f zgA = vfma(h, vAh[2], vfma(xv, vAx[2], vAb[2]));
            v2f zoA = vfma(h, vAh[3], vfma(xv, vAx[3], vAb[3]));
            v2f EiA = vexp2(ziA), EfA = vexp2(zfA), EgA = vexp2(zgA), EoA = vexp2(zoA);
            v2f w1 = EiA + one, w2 = EgA + one, w3 = EfA + one;
            v2f IG = w1 * w2;
            v2f Ra = vrcp2(IG * w3);
            v2f tt = vfma(w2, vL2, vNL4) * w3;   // (2L*u2 - 4L)*u3
            v2f num = vfma(C, IG, tt);
            C = num * Ra;                        // scaled cell: 2L*(f*c + i*tanh(g))
            v2f EcA = vexp2(C);
            v2f e1 = EcA - one, e2 = EcA + one;
            v2f Rb = vrcp2((EoA + one) * e2);
            h = e1 * Rb;                         // o * tanh(c)
            acc = vfma(h, wl2[p][t], acc);
        }
    }
    out[g] = acc.x + acc.y + bl;
}

extern "C" void kernel_launch(void* const* d_in, const int* in_sizes, int n_in,
                              void* d_out, int out_size, void* d_ws, size_t ws_size,
                              hipStream_t stream) {
    const float* x     = (const float*)d_in[0];
    const float* w_ih  = (const float*)d_in[1];
    const float* w_hh  = (const float*)d_in[2];
    const float* b_ih  = (const float*)d_in[3];
    const float* b_hh  = (const float*)d_in[4];
    const float* w_lin = (const float*)d_in[5];
    const float* b_lin = (const float*)d_in[6];
    float* out = (float*)d_out;

    const int n_groups = in_sizes[0] / 18;  // B/6 = 2097152
    const int grid = (n_groups + 255) / 256;
    lstm_head_kernel<<<grid, 256, 0, stream>>>(
        x, w_ih, w_hh, b_ih, b_hh, w_lin, b_lin, out, n_groups);
}